// Round 7
// baseline (447.046 us; speedup 1.0000x reference)
//
#include <hip/hip_runtime.h>
#include <stdint.h>

#define N_BATCH 32
#define CHN     256
#define HW      56
#define HP      58
#define HPT     7

// xpad layout (uint4 "cells" of 4 u32 = 128 channel-bits):
//   cell(n, hp, h, wp) = ((n*58 + hp)*2 + h)*58 + wp,  h = channel-half
#define XPAD_CELLS (N_BATCH * HP * 2 * HP)   // 215,296 cells
#define XPAD_U32   (XPAD_CELLS * 4)

// ---------------- weight binarization via ballot ----------------------------
__global__ __launch_bounds__(256) void binw_kernel(const float* __restrict__ wsrc,
                                                   uint32_t* __restrict__ wbits,
                                                   int* __restrict__ wpop) {
    __shared__ int part[9][4];
    int o = blockIdx.x;
    int t = threadIdx.x;
    int lane = t & 63, wv = t >> 6;
    const float* p = wsrc + ((size_t)o * 256 + t) * 9;
    float v[9];
#pragma unroll
    for (int tap = 0; tap < 9; tap++) v[tap] = p[tap];
#pragma unroll
    for (int tap = 0; tap < 9; tap++) {
        unsigned long long m = __ballot(v[tap] > 0.0f);
        if (lane == 0) {
            wbits[(size_t)(o * 9 + tap) * 8 + 2 * wv]     = (uint32_t)m;
            wbits[(size_t)(o * 9 + tap) * 8 + 2 * wv + 1] = (uint32_t)(m >> 32);
            part[tap][wv] = __builtin_popcountll(m);
        }
    }
    __syncthreads();
    if (t < 9) wpop[o * 9 + t] = part[t][0] + part[t][1] + part[t][2] + part[t][3];
}

// ---------------- x binarization: 16 channels/thread, shfl-merged -----------
// wave w: k-word = w&7, 32-quad group g32 = w>>3. lane: subq = lane&31,
// hf = lane>>5 (channel half of the word). 1568 blocks x 256 = 6272 waves.
__global__ __launch_bounds__(256) void binx_kernel(const float* __restrict__ x,
                                                   uint32_t* __restrict__ xpad) {
    int t    = threadIdx.x;
    int lane = t & 63;
    int w    = blockIdx.x * 4 + (t >> 6);   // wave id, 0..6271
    int k    = w & 7;
    int g32  = w >> 3;                      // 0..783
    int subq = lane & 31;
    int hf   = lane >> 5;
    int quad = g32 * 32 + subq;             // 0..25087
    int n    = quad / 784;
    int pq   = quad - n * 784;
    int c0   = k * 32 + hf * 16;

    const float4* src = (const float4*)x + ((size_t)(n * 256 + c0)) * 784 + pq;
    float4 v[16];
#pragma unroll
    for (int u = 0; u < 16; u++) v[u] = src[(size_t)u * 784];

    uint32_t m0 = 0, m1 = 0, m2 = 0, m3 = 0;
#pragma unroll
    for (int u = 0; u < 16; u++) {
        m0 |= (v[u].x > 0.0f ? 1u : 0u) << u;
        m1 |= (v[u].y > 0.0f ? 1u : 0u) << u;
        m2 |= (v[u].z > 0.0f ? 1u : 0u) << u;
        m3 |= (v[u].w > 0.0f ? 1u : 0u) << u;
    }
    uint32_t pA = m0 | (m1 << 16);
    uint32_t pB = m2 | (m3 << 16);
    uint32_t oA = __shfl_xor(pA, 32);
    uint32_t oB = __shfl_xor(pB, 32);
    if (hf == 0) {
        uint32_t b0 = (pA & 0xffffu) | ((oA & 0xffffu) << 16);
        uint32_t b1 = (pA >> 16)     | (oA & 0xffff0000u);
        uint32_t b2 = (pB & 0xffffu) | ((oB & 0xffffu) << 16);
        uint32_t b3 = (pB >> 16)     | (oB & 0xffff0000u);
        int h  = pq / 14;
        int wq = pq - h * 14;
        int w0 = wq * 4;
        uint32_t cell = ((uint32_t)(n * HP + h + 1) * 2 + (k >> 2)) * HP + (w0 + 1);
        uint32_t* dst = xpad + (size_t)cell * 4 + (k & 3);
        dst[0] = b0; dst[4] = b1; dst[8] = b2; dst[12] = b3;
    }
}

// ---------------- binary conv ----------------------------------------------
// grid (7 strips, 16 o-groups, 32 n), block 256 = 4 waves, all 64 lanes live.
// Strip s covers base pixels [s*64,(s+1)*64) -> row-groups {s,s+1} -> 16
// padded rows staged in LDS (1856 cells = 29.7 KB), reused by 16 o's
// (4 per wave, sequential). Weights in two half-channel passes (36 live).
__global__ __launch_bounds__(256) void conv_kernel(const uint32_t* __restrict__ xpad,
                                                   const uint32_t* __restrict__ wbits,
                                                   const int* __restrict__ wpop,
                                                   float* __restrict__ out) {
    __shared__ uint4 sx[1856];      // 29,696 B

    int t     = threadIdx.x;
    int lane  = t & 63;
    int wv    = __builtin_amdgcn_readfirstlane(t >> 6);
    int strip = blockIdx.x;         // 0..6
    int og    = blockIdx.y;         // 0..15
    int n     = blockIdx.z;
    int ob    = og * 16 + wv * 4;   // first o of this wave (uniform)

    // stage 16 padded rows: 1856 contiguous cells
    const uint4* xg = (const uint4*)xpad + (size_t)(n * HP + strip * 7) * (2 * HP);
    {
        uint4 r[7];
#pragma unroll
        for (int i = 0; i < 7; i++) r[i] = xg[t + 256 * i];
#pragma unroll
        for (int i = 0; i < 7; i++) sx[t + 256 * i] = r[i];
        if (t < 64) sx[1792 + t] = xg[1792 + t];
    }
    __syncthreads();

    int b    = strip * 64 + lane;   // base pixel, 0..447
    int hb_i = b / 56;              // row group 0..7
    int w    = b - hb_i * 56;       // col 0..55
    int r0   = (hb_i - strip) * 7;  // 0 or 7: row offset in staged window
    const char* sxb = (const char*)sx + ((r0 * 2 * HP) + w) * 16;

#pragma unroll 1
    for (int oi = 0; oi < 4; oi++) {
        int o = ob + oi;
        const uint32_t* wa = wbits + (size_t)o * 72;   // wave-uniform

        int acc[HPT];
#pragma unroll
        for (int r = 0; r < HPT; r++) acc[r] = 0;

#pragma unroll
        for (int h = 0; h < 2; h++) {
            uint32_t Wh[36];
#pragma unroll
            for (int tap = 0; tap < 9; tap++)
#pragma unroll
                for (int i = 0; i < 4; i++)
                    Wh[tap * 4 + i] = wa[tap * 8 + h * 4 + i];
#pragma unroll
            for (int j = 0; j < HPT + 2; j++) {
                uint4 X0 = *(const uint4*)(sxb + ((j * 2 + h) * HP + 0) * 16);
                uint4 X1 = *(const uint4*)(sxb + ((j * 2 + h) * HP + 1) * 16);
                uint4 X2 = *(const uint4*)(sxb + ((j * 2 + h) * HP + 2) * 16);
#pragma unroll
                for (int dh = 0; dh < 3; dh++) {
                    int r = j - dh;
                    if (r >= 0 && r < HPT) {
#pragma unroll
                        for (int dw = 0; dw < 3; dw++) {
                            uint4 X = (dw == 0) ? X0 : (dw == 1) ? X1 : X2;
                            int ta = (dh * 3 + dw) * 4;
                            acc[r] += __builtin_popcount(X.x ^ Wh[ta + 0])
                                    + __builtin_popcount(X.y ^ Wh[ta + 1])
                                    + __builtin_popcount(X.z ^ Wh[ta + 2])
                                    + __builtin_popcount(X.w ^ Wh[ta + 3]);
                        }
                    }
                }
            }
        }

        const int* wpa = wpop + (size_t)o * 9;
        int pa[9];
#pragma unroll
        for (int tp = 0; tp < 9; tp++) pa[tp] = wpa[tp];
        float* oa = out + ((size_t)(n * 256 + o)) * 3136 + hb_i * 7 * 56 + w;
        bool edge_w = (w == 0) | (w == 55);
#pragma unroll
        for (int r = 0; r < HPT; r++) {
            int hh = hb_i * 7 + r;
            int va = 2304 - 2 * acc[r];
            if (edge_w | (hh == 0) | (hh == 55)) {
                int ca = 0;
#pragma unroll
                for (int dh = -1; dh <= 1; dh++)
#pragma unroll
                    for (int dw = -1; dw <= 1; dw++)
                        if ((unsigned)(hh + dh) >= 56u || (unsigned)(w + dw) >= 56u)
                            ca += 256 - 2 * pa[(dh + 1) * 3 + (dw + 1)];
                va -= ca;
            }
            oa[(size_t)r * 56] = (float)va;
        }
    }
}

extern "C" void kernel_launch(void* const* d_in, const int* in_sizes, int n_in,
                              void* d_out, int out_size, void* d_ws, size_t ws_size,
                              hipStream_t stream) {
    const float* x    = (const float*)d_in[0];
    const float* wsrc = (const float*)d_in[1];
    float* out = (float*)d_out;

    uint32_t* xpad  = (uint32_t*)d_ws;                    // 3.44 MB
    uint32_t* wbits = xpad + XPAD_U32;                    // 18432 u32
    int*      wpop  = (int*)(wbits + 256 * 9 * 8);        // 2304 int

    hipMemsetAsync(xpad, 0, (size_t)XPAD_U32 * 4, stream);
    binw_kernel<<<256, 256, 0, stream>>>(wsrc, wbits, wpop);
    binx_kernel<<<1568, 256, 0, stream>>>(x, xpad);
    conv_kernel<<<dim3(7, 16, N_BATCH), 256, 0, stream>>>(xpad, wbits, wpop, out);
}

// Round 8
// 367.292 us; speedup vs baseline: 1.2171x; 1.2171x over previous
//
#include <hip/hip_runtime.h>
#include <stdint.h>

#define N_BATCH 32
#define CHN     256
#define HW      56
#define HP      58
#define HPT     7

// xpad layout (uint4 "cells" of 4 u32 = 128 channel-bits):
//   cell(n, hp, h, wp) = ((n*58 + hp)*2 + h)*58 + wp,  h = channel-half
#define XPAD_CELLS (N_BATCH * HP * 2 * HP)   // 215,296 cells
#define XPAD_U32   (XPAD_CELLS * 4)

// ---------------- weight binarization via ballot ----------------------------
__global__ __launch_bounds__(256) void binw_kernel(const float* __restrict__ wsrc,
                                                   uint32_t* __restrict__ wbits,
                                                   int* __restrict__ wpop) {
    __shared__ int part[9][4];
    int o = blockIdx.x;
    int t = threadIdx.x;
    int lane = t & 63, wv = t >> 6;
    const float* p = wsrc + ((size_t)o * 256 + t) * 9;
    float v[9];
#pragma unroll
    for (int tap = 0; tap < 9; tap++) v[tap] = p[tap];
#pragma unroll
    for (int tap = 0; tap < 9; tap++) {
        unsigned long long m = __ballot(v[tap] > 0.0f);
        if (lane == 0) {
            wbits[(size_t)(o * 9 + tap) * 8 + 2 * wv]     = (uint32_t)m;
            wbits[(size_t)(o * 9 + tap) * 8 + 2 * wv + 1] = (uint32_t)(m >> 32);
            part[tap][wv] = __builtin_popcountll(m);
        }
    }
    __syncthreads();
    if (t < 9) wpop[o * 9 + t] = part[t][0] + part[t][1] + part[t][2] + part[t][3];
}

// ---------------- x binarization (round-6 proven version) -------------------
__global__ __launch_bounds__(256) void binx_kernel(const float* __restrict__ x,
                                                   uint32_t* __restrict__ xpad) {
    int t    = threadIdx.x;
    int lane = t & 63;
    int fw   = blockIdx.x * 4 + (t >> 6);   // flat wave id, 0..3135
    int k    = fw & 7;                      // word index (channels 32k..32k+31)
    int q    = (fw >> 3) * 64 + lane;       // quad id, 0..25087
    int n    = q / 784;
    int pq   = q - n * 784;                 // quad within plane

    const float4* src = (const float4*)x + ((size_t)(n * 256 + k * 32)) * 784 + pq;
    uint32_t b0 = 0, b1 = 0, b2 = 0, b3 = 0;
#pragma unroll
    for (int g = 0; g < 4; g++) {
        float4 v[8];
#pragma unroll
        for (int u = 0; u < 8; u++) v[u] = src[(size_t)(g * 8 + u) * 784];
#pragma unroll
        for (int u = 0; u < 8; u++) {
            int cc = g * 8 + u;
            b0 |= (v[u].x > 0.0f ? 1u : 0u) << cc;
            b1 |= (v[u].y > 0.0f ? 1u : 0u) << cc;
            b2 |= (v[u].z > 0.0f ? 1u : 0u) << cc;
            b3 |= (v[u].w > 0.0f ? 1u : 0u) << cc;
        }
    }
    int h  = pq / 14;
    int wq = pq - h * 14;
    int w0 = wq * 4;
    uint32_t cell = ((uint32_t)(n * HP + h + 1) * 2 + (k >> 2)) * HP + (w0 + 1);
    uint32_t* dst = xpad + (size_t)cell * 4 + (k & 3);
    dst[0] = b0; dst[4] = b1; dst[8] = b2; dst[12] = b3;
}

// ---------------- binary conv ----------------------------------------------
// grid (8 strips, 16 o-groups, 32 n) = 4096 blocks, 256 thr = 4 waves.
// Round-6 chassis: lane = column, contiguous LDS mapping (0 conflicts),
// simple staging loop. New: 4 sequential o per wave (unroll 1, o pinned
// scalar via readfirstlane each iteration) amortizes staging 4x; single
// weight pass (W[72] live — round-1 proved ~104 VGPR is enough).
__global__ __launch_bounds__(256) void conv_kernel(const uint32_t* __restrict__ xpad,
                                                   const uint32_t* __restrict__ wbits,
                                                   const int* __restrict__ wpop,
                                                   float* __restrict__ out) {
    __shared__ uint4 sx[1044];      // 16.7 KB

    int t     = threadIdx.x;
    int lane  = t & 63;
    int wv    = t >> 6;
    int strip = blockIdx.x;         // 0..7
    int og    = blockIdx.y;         // 0..15
    int n     = blockIdx.z;
    int hb    = strip * HPT;

    // stage X strip: 1044 contiguous cells, plain loads, uniform loop bound
    const uint4* xg = (const uint4*)xpad + (size_t)(n * HP + hb) * (2 * HP);
    for (int i = t; i < 1044; i += 256)
        sx[i] = xg[i];
    __syncthreads();

    const char* sxb = (const char*)sx + lane * 16; // one addr reg, imm offsets

#pragma unroll 1
    for (int oi = 0; oi < 4; oi++) {
        int o = __builtin_amdgcn_readfirstlane(og * 16 + wv * 4 + oi);
        const uint32_t* wa = wbits + (size_t)o * 72;   // scalar address

        uint32_t W[72];
#pragma unroll
        for (int i = 0; i < 72; i++) W[i] = wa[i];

        int acc[HPT];
#pragma unroll
        for (int r = 0; r < HPT; r++) acc[r] = 0;

#pragma unroll
        for (int j = 0; j < HPT + 2; j++) {
            uint4 X0a = *(const uint4*)(sxb + ((j * 2 + 0) * HP + 0) * 16);
            uint4 X1a = *(const uint4*)(sxb + ((j * 2 + 0) * HP + 1) * 16);
            uint4 X2a = *(const uint4*)(sxb + ((j * 2 + 0) * HP + 2) * 16);
            uint4 X0b = *(const uint4*)(sxb + ((j * 2 + 1) * HP + 0) * 16);
            uint4 X1b = *(const uint4*)(sxb + ((j * 2 + 1) * HP + 1) * 16);
            uint4 X2b = *(const uint4*)(sxb + ((j * 2 + 1) * HP + 2) * 16);
#pragma unroll
            for (int dh = 0; dh < 3; dh++) {
                int r = j - dh;
                if (r >= 0 && r < HPT) {
#pragma unroll
                    for (int dw = 0; dw < 3; dw++) {
                        uint4 Xa = (dw == 0) ? X0a : (dw == 1) ? X1a : X2a;
                        uint4 Xb = (dw == 0) ? X0b : (dw == 1) ? X1b : X2b;
                        int ta = (dh * 3 + dw) * 8;
                        acc[r] += __builtin_popcount(Xa.x ^ W[ta + 0])
                                + __builtin_popcount(Xa.y ^ W[ta + 1])
                                + __builtin_popcount(Xa.z ^ W[ta + 2])
                                + __builtin_popcount(Xa.w ^ W[ta + 3])
                                + __builtin_popcount(Xb.x ^ W[ta + 4])
                                + __builtin_popcount(Xb.y ^ W[ta + 5])
                                + __builtin_popcount(Xb.z ^ W[ta + 6])
                                + __builtin_popcount(Xb.w ^ W[ta + 7]);
                    }
                }
            }
        }

        if (lane < 56) {
            int w = lane;
            const int* wpa = wpop + (size_t)o * 9;     // scalar address
            int pa[9];
#pragma unroll
            for (int tp = 0; tp < 9; tp++) pa[tp] = wpa[tp];
            float* oa = out + (((size_t)n * 256 + o) * 56 + hb) * 56 + w;
            bool edge_w = (w == 0) | (w == 55);
#pragma unroll
            for (int r = 0; r < HPT; r++) {
                int hh = hb + r;
                int va = 2304 - 2 * acc[r];
                if (edge_w | (hh == 0) | (hh == 55)) {
                    int ca = 0;
#pragma unroll
                    for (int dh = -1; dh <= 1; dh++)
#pragma unroll
                        for (int dw = -1; dw <= 1; dw++)
                            if ((unsigned)(hh + dh) >= 56u || (unsigned)(w + dw) >= 56u)
                                ca += 256 - 2 * pa[(dh + 1) * 3 + (dw + 1)];
                    va -= ca;
                }
                oa[(size_t)r * 56] = (float)va;
            }
        }
    }
}

extern "C" void kernel_launch(void* const* d_in, const int* in_sizes, int n_in,
                              void* d_out, int out_size, void* d_ws, size_t ws_size,
                              hipStream_t stream) {
    const float* x    = (const float*)d_in[0];
    const float* wsrc = (const float*)d_in[1];
    float* out = (float*)d_out;

    uint32_t* xpad  = (uint32_t*)d_ws;                    // 3.44 MB
    uint32_t* wbits = xpad + XPAD_U32;                    // 18432 u32
    int*      wpop  = (int*)(wbits + 256 * 9 * 8);        // 2304 int

    hipMemsetAsync(xpad, 0, (size_t)XPAD_U32 * 4, stream);
    binw_kernel<<<256, 256, 0, stream>>>(wsrc, wbits, wpop);
    binx_kernel<<<784, 256, 0, stream>>>(x, xpad);
    conv_kernel<<<dim3(8, 16, N_BATCH), 256, 0, stream>>>(xpad, wbits, wpop, out);
}

// Round 9
// 363.337 us; speedup vs baseline: 1.2304x; 1.0109x over previous
//
#include <hip/hip_runtime.h>
#include <stdint.h>

#define N_BATCH 32
#define CHN     256
#define HW      56
#define HP      58
#define HPT     7

// xpad layout (uint4 "cells" of 4 u32 = 128 channel-bits):
//   cell(n, hp, h, wp) = ((n*58 + hp)*2 + h)*58 + wp,  h = channel-half
#define XPAD_CELLS (N_BATCH * HP * 2 * HP)   // 215,296 cells
#define XPAD_U32   (XPAD_CELLS * 4)

// ---------------- fused prep: binx (784) + border zeros (57) + binw (256) ---
__global__ __launch_bounds__(256) void prep_kernel(const float* __restrict__ x,
                                                   const float* __restrict__ wsrc,
                                                   uint32_t* __restrict__ xpad,
                                                   uint32_t* __restrict__ wbits,
                                                   int* __restrict__ wpop) {
    __shared__ int part[9][4];
    int bid  = blockIdx.x;
    int t    = threadIdx.x;
    int lane = t & 63;

    if (bid < 784) {
        // ---- binx interior (round-6/8 proven body) ----
        int fw   = bid * 4 + (t >> 6);          // flat wave id, 0..3135
        int k    = fw & 7;                      // word index (channels 32k..)
        int q    = (fw >> 3) * 64 + lane;       // quad id, 0..25087
        int n    = q / 784;
        int pq   = q - n * 784;                 // quad within plane

        const float4* src = (const float4*)x + ((size_t)(n * 256 + k * 32)) * 784 + pq;
        uint32_t b0 = 0, b1 = 0, b2 = 0, b3 = 0;
#pragma unroll
        for (int g = 0; g < 4; g++) {
            float4 v[8];
#pragma unroll
            for (int u = 0; u < 8; u++) v[u] = src[(size_t)(g * 8 + u) * 784];
#pragma unroll
            for (int u = 0; u < 8; u++) {
                int cc = g * 8 + u;
                b0 |= (v[u].x > 0.0f ? 1u : 0u) << cc;
                b1 |= (v[u].y > 0.0f ? 1u : 0u) << cc;
                b2 |= (v[u].z > 0.0f ? 1u : 0u) << cc;
                b3 |= (v[u].w > 0.0f ? 1u : 0u) << cc;
            }
        }
        int h  = pq / 14;
        int wq = pq - h * 14;
        int w0 = wq * 4;
        uint32_t cell = ((uint32_t)(n * HP + h + 1) * 2 + (k >> 2)) * HP + (w0 + 1);
        uint32_t* dst = xpad + (size_t)cell * 4 + (k & 3);
        dst[0] = b0; dst[4] = b1; dst[8] = b2; dst[12] = b3;
    } else if (bid < 841) {
        // ---- border zero-fill (replaces the memset): 14,592 border cells ----
        int u = (bid - 784) * 256 + t;          // 0..14591
        if (u < 14592) {
            int p = u / 228;                    // (n, half) pair
            int e = u - p * 228;
            int n = p >> 1, h = p & 1;
            int hp, wp;
            if (e < 58)       { hp = 0;       wp = e;       }
            else if (e < 116) { hp = 57;      wp = e - 58;  }
            else if (e < 172) { hp = e - 115; wp = 0;       }   // rows 1..56
            else              { hp = e - 171; wp = 57;      }   // rows 1..56
            uint32_t cell = ((uint32_t)(n * HP + hp) * 2 + h) * HP + wp;
            ((uint4*)xpad)[cell] = make_uint4(0u, 0u, 0u, 0u);
        }
    } else {
        // ---- binw via ballot (round-6/8 proven body), o = bid - 841 ----
        int o  = bid - 841;
        int wv = t >> 6;
        const float* p = wsrc + ((size_t)o * 256 + t) * 9;
        float v[9];
#pragma unroll
        for (int tap = 0; tap < 9; tap++) v[tap] = p[tap];
#pragma unroll
        for (int tap = 0; tap < 9; tap++) {
            unsigned long long m = __ballot(v[tap] > 0.0f);
            if (lane == 0) {
                wbits[(size_t)(o * 9 + tap) * 8 + 2 * wv]     = (uint32_t)m;
                wbits[(size_t)(o * 9 + tap) * 8 + 2 * wv + 1] = (uint32_t)(m >> 32);
                part[tap][wv] = __builtin_popcountll(m);
            }
        }
        __syncthreads();
        if (t < 9) wpop[o * 9 + t] = part[t][0] + part[t][1] + part[t][2] + part[t][3];
    }
}

// ---------------- binary conv (bit-for-bit round 8) -------------------------
__global__ __launch_bounds__(256) void conv_kernel(const uint32_t* __restrict__ xpad,
                                                   const uint32_t* __restrict__ wbits,
                                                   const int* __restrict__ wpop,
                                                   float* __restrict__ out) {
    __shared__ uint4 sx[1044];      // 16.7 KB

    int t     = threadIdx.x;
    int lane  = t & 63;
    int wv    = t >> 6;
    int strip = blockIdx.x;         // 0..7
    int og    = blockIdx.y;         // 0..15
    int n     = blockIdx.z;
    int hb    = strip * HPT;

    const uint4* xg = (const uint4*)xpad + (size_t)(n * HP + hb) * (2 * HP);
    for (int i = t; i < 1044; i += 256)
        sx[i] = xg[i];
    __syncthreads();

    const char* sxb = (const char*)sx + lane * 16;

#pragma unroll 1
    for (int oi = 0; oi < 4; oi++) {
        int o = __builtin_amdgcn_readfirstlane(og * 16 + wv * 4 + oi);
        const uint32_t* wa = wbits + (size_t)o * 72;

        uint32_t W[72];
#pragma unroll
        for (int i = 0; i < 72; i++) W[i] = wa[i];

        int acc[HPT];
#pragma unroll
        for (int r = 0; r < HPT; r++) acc[r] = 0;

#pragma unroll
        for (int j = 0; j < HPT + 2; j++) {
            uint4 X0a = *(const uint4*)(sxb + ((j * 2 + 0) * HP + 0) * 16);
            uint4 X1a = *(const uint4*)(sxb + ((j * 2 + 0) * HP + 1) * 16);
            uint4 X2a = *(const uint4*)(sxb + ((j * 2 + 0) * HP + 2) * 16);
            uint4 X0b = *(const uint4*)(sxb + ((j * 2 + 1) * HP + 0) * 16);
            uint4 X1b = *(const uint4*)(sxb + ((j * 2 + 1) * HP + 1) * 16);
            uint4 X2b = *(const uint4*)(sxb + ((j * 2 + 1) * HP + 2) * 16);
#pragma unroll
            for (int dh = 0; dh < 3; dh++) {
                int r = j - dh;
                if (r >= 0 && r < HPT) {
#pragma unroll
                    for (int dw = 0; dw < 3; dw++) {
                        uint4 Xa = (dw == 0) ? X0a : (dw == 1) ? X1a : X2a;
                        uint4 Xb = (dw == 0) ? X0b : (dw == 1) ? X1b : X2b;
                        int ta = (dh * 3 + dw) * 8;
                        acc[r] += __builtin_popcount(Xa.x ^ W[ta + 0])
                                + __builtin_popcount(Xa.y ^ W[ta + 1])
                                + __builtin_popcount(Xa.z ^ W[ta + 2])
                                + __builtin_popcount(Xa.w ^ W[ta + 3])
                                + __builtin_popcount(Xb.x ^ W[ta + 4])
                                + __builtin_popcount(Xb.y ^ W[ta + 5])
                                + __builtin_popcount(Xb.z ^ W[ta + 6])
                                + __builtin_popcount(Xb.w ^ W[ta + 7]);
                    }
                }
            }
        }

        if (lane < 56) {
            int w = lane;
            const int* wpa = wpop + (size_t)o * 9;
            int pa[9];
#pragma unroll
            for (int tp = 0; tp < 9; tp++) pa[tp] = wpa[tp];
            float* oa = out + (((size_t)n * 256 + o) * 56 + hb) * 56 + w;
            bool edge_w = (w == 0) | (w == 55);
#pragma unroll
            for (int r = 0; r < HPT; r++) {
                int hh = hb + r;
                int va = 2304 - 2 * acc[r];
                if (edge_w | (hh == 0) | (hh == 55)) {
                    int ca = 0;
#pragma unroll
                    for (int dh = -1; dh <= 1; dh++)
#pragma unroll
                        for (int dw = -1; dw <= 1; dw++)
                            if ((unsigned)(hh + dh) >= 56u || (unsigned)(w + dw) >= 56u)
                                ca += 256 - 2 * pa[(dh + 1) * 3 + (dw + 1)];
                    va -= ca;
                }
                oa[(size_t)r * 56] = (float)va;
            }
        }
    }
}

extern "C" void kernel_launch(void* const* d_in, const int* in_sizes, int n_in,
                              void* d_out, int out_size, void* d_ws, size_t ws_size,
                              hipStream_t stream) {
    const float* x    = (const float*)d_in[0];
    const float* wsrc = (const float*)d_in[1];
    float* out = (float*)d_out;

    uint32_t* xpad  = (uint32_t*)d_ws;                    // 3.44 MB
    uint32_t* wbits = xpad + XPAD_U32;                    // 18432 u32
    int*      wpop  = (int*)(wbits + 256 * 9 * 8);        // 2304 int

    prep_kernel<<<1097, 256, 0, stream>>>(x, wsrc, xpad, wbits, wpop);
    conv_kernel<<<dim3(8, 16, N_BATCH), 256, 0, stream>>>(xpad, wbits, wpop, out);
}

// Round 10
// 361.301 us; speedup vs baseline: 1.2373x; 1.0056x over previous
//
#include <hip/hip_runtime.h>
#include <stdint.h>

#define N_BATCH 32
#define CHN     256
#define HW      56
#define HP      58
#define HPT     7

// xpad layout (uint4 "cells" of 4 u32 = 128 channel-bits):
//   cell(n, hp, h, wp) = ((n*58 + hp)*2 + h)*58 + wp,  h = channel-half
#define XPAD_CELLS (N_BATCH * HP * 2 * HP)   // 215,296 cells
#define XPAD_U32   (XPAD_CELLS * 4)

// ---------------- fused prep ------------------------------------------------
// blocks [0,784):   binx — thread = (pixel, channel-half), coalesced uint4 write
// blocks [784,841): border zero-fill (replaces memset)
// blocks [841,1097): binw via ballot
__global__ __launch_bounds__(256) void prep_kernel(const float* __restrict__ x,
                                                   const float* __restrict__ wsrc,
                                                   uint32_t* __restrict__ xpad,
                                                   uint32_t* __restrict__ wbits,
                                                   int* __restrict__ wpop) {
    __shared__ int part[9][4];
    int bid  = blockIdx.x;
    int t    = threadIdx.x;
    int lane = t & 63;

    if (bid < 784) {
        // ---- binx: one full cell (4 words = 128 channels) per thread ----
        int tid = bid * 256 + t;          // 0..200703
        int n   = tid / 6272;             // 6272 = 3136 px * 2 halves
        int rem = tid - n * 6272;
        int hf  = rem / 3136;             // channel half (wave-uniform: 3136=49 waves)
        int pq  = rem - hf * 3136;        // pixel in plane; lane-consecutive

        const float* src = x + ((size_t)(n * 256 + hf * 128)) * 3136 + pq;
        uint32_t b0 = 0, b1 = 0, b2 = 0, b3 = 0;
#pragma unroll
        for (int g = 0; g < 8; g++) {
            float v[16];
#pragma unroll
            for (int i = 0; i < 16; i++) v[i] = src[(size_t)(g * 16 + i) * 3136];
#pragma unroll
            for (int i = 0; i < 16; i++) {
                int c = g * 16 + i;       // 0..127 within half
                uint32_t b = v[i] > 0.0f ? 1u : 0u;
                if ((c >> 5) == 0) b0 |= b << (c & 31);
                else if ((c >> 5) == 1) b1 |= b << (c & 31);
                else if ((c >> 5) == 2) b2 |= b << (c & 31);
                else b3 |= b << (c & 31);
            }
        }
        int h = pq / 56;
        int w = pq - h * 56;
        uint32_t cell = ((uint32_t)(n * HP + h + 1) * 2 + hf) * HP + (w + 1);
        ((uint4*)xpad)[cell] = make_uint4(b0, b1, b2, b3);   // 16B/lane, coalesced
    } else if (bid < 841) {
        // ---- border zero-fill: 14,592 border cells ----
        int u = (bid - 784) * 256 + t;
        if (u < 14592) {
            int p = u / 228;
            int e = u - p * 228;
            int n = p >> 1, h = p & 1;
            int hp, wp;
            if (e < 58)       { hp = 0;       wp = e;       }
            else if (e < 116) { hp = 57;      wp = e - 58;  }
            else if (e < 172) { hp = e - 115; wp = 0;       }
            else              { hp = e - 171; wp = 57;      }
            uint32_t cell = ((uint32_t)(n * HP + hp) * 2 + h) * HP + wp;
            ((uint4*)xpad)[cell] = make_uint4(0u, 0u, 0u, 0u);
        }
    } else {
        // ---- binw via ballot ----
        int o  = bid - 841;
        int wv = t >> 6;
        const float* p = wsrc + ((size_t)o * 256 + t) * 9;
        float v[9];
#pragma unroll
        for (int tap = 0; tap < 9; tap++) v[tap] = p[tap];
#pragma unroll
        for (int tap = 0; tap < 9; tap++) {
            unsigned long long m = __ballot(v[tap] > 0.0f);
            if (lane == 0) {
                wbits[(size_t)(o * 9 + tap) * 8 + 2 * wv]     = (uint32_t)m;
                wbits[(size_t)(o * 9 + tap) * 8 + 2 * wv + 1] = (uint32_t)(m >> 32);
                part[tap][wv] = __builtin_popcountll(m);
            }
        }
        __syncthreads();
        if (t < 9) wpop[o * 9 + t] = part[t][0] + part[t][1] + part[t][2] + part[t][3];
    }
}

// ---------------- binary conv (bit-for-bit round 8/9) -----------------------
__global__ __launch_bounds__(256) void conv_kernel(const uint32_t* __restrict__ xpad,
                                                   const uint32_t* __restrict__ wbits,
                                                   const int* __restrict__ wpop,
                                                   float* __restrict__ out) {
    __shared__ uint4 sx[1044];      // 16.7 KB

    int t     = threadIdx.x;
    int lane  = t & 63;
    int wv    = t >> 6;
    int strip = blockIdx.x;         // 0..7
    int og    = blockIdx.y;         // 0..15
    int n     = blockIdx.z;
    int hb    = strip * HPT;

    const uint4* xg = (const uint4*)xpad + (size_t)(n * HP + hb) * (2 * HP);
    for (int i = t; i < 1044; i += 256)
        sx[i] = xg[i];
    __syncthreads();

    const char* sxb = (const char*)sx + lane * 16;

#pragma unroll 1
    for (int oi = 0; oi < 4; oi++) {
        int o = __builtin_amdgcn_readfirstlane(og * 16 + wv * 4 + oi);
        const uint32_t* wa = wbits + (size_t)o * 72;

        uint32_t W[72];
#pragma unroll
        for (int i = 0; i < 72; i++) W[i] = wa[i];

        int acc[HPT];
#pragma unroll
        for (int r = 0; r < HPT; r++) acc[r] = 0;

#pragma unroll
        for (int j = 0; j < HPT + 2; j++) {
            uint4 X0a = *(const uint4*)(sxb + ((j * 2 + 0) * HP + 0) * 16);
            uint4 X1a = *(const uint4*)(sxb + ((j * 2 + 0) * HP + 1) * 16);
            uint4 X2a = *(const uint4*)(sxb + ((j * 2 + 0) * HP + 2) * 16);
            uint4 X0b = *(const uint4*)(sxb + ((j * 2 + 1) * HP + 0) * 16);
            uint4 X1b = *(const uint4*)(sxb + ((j * 2 + 1) * HP + 1) * 16);
            uint4 X2b = *(const uint4*)(sxb + ((j * 2 + 1) * HP + 2) * 16);
#pragma unroll
            for (int dh = 0; dh < 3; dh++) {
                int r = j - dh;
                if (r >= 0 && r < HPT) {
#pragma unroll
                    for (int dw = 0; dw < 3; dw++) {
                        uint4 Xa = (dw == 0) ? X0a : (dw == 1) ? X1a : X2a;
                        uint4 Xb = (dw == 0) ? X0b : (dw == 1) ? X1b : X2b;
                        int ta = (dh * 3 + dw) * 8;
                        acc[r] += __builtin_popcount(Xa.x ^ W[ta + 0])
                                + __builtin_popcount(Xa.y ^ W[ta + 1])
                                + __builtin_popcount(Xa.z ^ W[ta + 2])
                                + __builtin_popcount(Xa.w ^ W[ta + 3])
                                + __builtin_popcount(Xb.x ^ W[ta + 4])
                                + __builtin_popcount(Xb.y ^ W[ta + 5])
                                + __builtin_popcount(Xb.z ^ W[ta + 6])
                                + __builtin_popcount(Xb.w ^ W[ta + 7]);
                    }
                }
            }
        }

        if (lane < 56) {
            int w = lane;
            const int* wpa = wpop + (size_t)o * 9;
            int pa[9];
#pragma unroll
            for (int tp = 0; tp < 9; tp++) pa[tp] = wpa[tp];
            float* oa = out + (((size_t)n * 256 + o) * 56 + hb) * 56 + w;
            bool edge_w = (w == 0) | (w == 55);
#pragma unroll
            for (int r = 0; r < HPT; r++) {
                int hh = hb + r;
                int va = 2304 - 2 * acc[r];
                if (edge_w | (hh == 0) | (hh == 55)) {
                    int ca = 0;
#pragma unroll
                    for (int dh = -1; dh <= 1; dh++)
#pragma unroll
                        for (int dw = -1; dw <= 1; dw++)
                            if ((unsigned)(hh + dh) >= 56u || (unsigned)(w + dw) >= 56u)
                                ca += 256 - 2 * pa[(dh + 1) * 3 + (dw + 1)];
                    va -= ca;
                }
                oa[(size_t)r * 56] = (float)va;
            }
        }
    }
}

extern "C" void kernel_launch(void* const* d_in, const int* in_sizes, int n_in,
                              void* d_out, int out_size, void* d_ws, size_t ws_size,
                              hipStream_t stream) {
    const float* x    = (const float*)d_in[0];
    const float* wsrc = (const float*)d_in[1];
    float* out = (float*)d_out;

    uint32_t* xpad  = (uint32_t*)d_ws;                    // 3.44 MB
    uint32_t* wbits = xpad + XPAD_U32;                    // 18432 u32
    int*      wpop  = (int*)(wbits + 256 * 9 * 8);        // 2304 int

    prep_kernel<<<1097, 256, 0, stream>>>(x, wsrc, xpad, wbits, wpop);
    conv_kernel<<<dim3(8, 16, N_BATCH), 256, 0, stream>>>(xpad, wbits, wpop, out);
}